// Round 1
// baseline (260.770 us; speedup 1.0000x reference)
//
#include <hip/hip_runtime.h>

// Problem constants (fixed by setup_inputs)
#define B_   8
#define C_   64
#define O_   64
#define H_   128
#define W_   128
#define HO_  128
#define WO_  128
#define K2_  9
#define MOFF 18          // 2*K*K offset channels
#define PLANE (H_*W_)    // 16384
#define KTOT 576         // C_*K2_
// LDS row stride in bf16 units: 304 B = 19 x 16B groups. Group stride 19 mod 32
// (odd) -> b128 ops across consecutive rows are conflict-free (measured 0 conflicts).
#define LSTRIDE 152
#define NPX  64          // pixels per block = HALF output row (R10: occupancy 4->8 blocks/CU)

typedef short bf16x8 __attribute__((ext_vector_type(8)));
typedef float f32x16 __attribute__((ext_vector_type(16)));

__device__ __forceinline__ unsigned short f2bf(float f) {
    // round-to-nearest-even fp32 -> bf16
    unsigned u = __float_as_uint(f);
    u += 0x7fff + ((u >> 16) & 1);
    return (unsigned short)(u >> 16);
}
__device__ __forceinline__ float bf2f(short v) {
    return __uint_as_float(((unsigned)(unsigned short)v) << 16);
}

// ---------------------------------------------------------------------------
// cvt_all: both weight tensors -> bf16 rows in TAP-MAJOR chunk order:
//   pos = cc*144 + t*16 + cl  <->  w[o][c = cc*16+cl][tap t]
// rows 0..63   -> main conv weights  (wbf)
// rows 64..95  -> offset conv weights (wobf = wbf + 64*KTOT; o>=18 zero)
// Merged into one launch (was 2 kernels).
// ---------------------------------------------------------------------------
__global__ __launch_bounds__(256) void cvt_all_kernel(const float* __restrict__ w,
                                                      const float* __restrict__ w_off,
                                                      unsigned short* __restrict__ wbf) {
    int i = blockIdx.x * 256 + threadIdx.x;     // 96*576 = 55296
    if (i >= 96 * KTOT) return;
    int o = i / KTOT, pos = i % KTOT;
    int cc = pos / 144, r = pos % 144, t = r / 16, cl = r % 16;
    int c = cc * 16 + cl;
    unsigned short v;
    if (o < O_)             v = f2bf(w[o * KTOT + c * 9 + t]);
    else if (o < O_ + MOFF) v = f2bf(w_off[(o - O_) * KTOT + c * 9 + t]);
    else                    v = 0;
    wbf[i] = v;
}

// ---------------------------------------------------------------------------
// Chunk-major NHWC bf16 transpose:
//   xt[((cc*B + b)*PLANE + y*W + px)*16 + cl] = bf16(x[((b*64 + cc*16+cl)*H+y)*W+px])
// ---------------------------------------------------------------------------
__global__ __launch_bounds__(256) void nhwc_kernel(const float* __restrict__ x,
                                                   unsigned short* __restrict__ xt) {
    __shared__ unsigned short T[64 * 130];      // stride 130 (odd 16B groups)
    const int tid = threadIdx.x;
    const int b = blockIdx.x & 7;
    const int y = blockIdx.x >> 3;
    const float* src = x + (size_t)b * C_ * PLANE + y * W_;
    for (int i = tid; i < 64 * 128; i += 256) {
        int c = i >> 7, px = i & 127;
        T[c * 130 + px] = f2bf(src[c * PLANE + px]);
    }
    __syncthreads();
    for (int j = tid; j < 128 * 4; j += 256) {
        int cc = j >> 7, px = j & 127;
        unsigned short* dst = xt + ((size_t)(cc * B_ + b) * PLANE + y * W_ + px) * 16;
        ushort4 v0 = { T[(cc*16+ 0)*130+px], T[(cc*16+ 1)*130+px],
                       T[(cc*16+ 2)*130+px], T[(cc*16+ 3)*130+px] };
        ushort4 v1 = { T[(cc*16+ 4)*130+px], T[(cc*16+ 5)*130+px],
                       T[(cc*16+ 6)*130+px], T[(cc*16+ 7)*130+px] };
        ushort4 v2 = { T[(cc*16+ 8)*130+px], T[(cc*16+ 9)*130+px],
                       T[(cc*16+10)*130+px], T[(cc*16+11)*130+px] };
        ushort4 v3 = { T[(cc*16+12)*130+px], T[(cc*16+13)*130+px],
                       T[(cc*16+14)*130+px], T[(cc*16+15)*130+px] };
        *(ushort4*)(dst)      = v0;
        *(ushort4*)(dst + 4)  = v1;
        *(ushort4*)(dst + 8)  = v2;
        *(ushort4*)(dst + 12) = v3;
    }
}

// ---------------------------------------------------------------------------
// FUSED offset-conv + deformable-conv, HALF-ROW blocks (R10).
// Block = (b, ho, half), 256 threads = 4 waves, N = 64 pixels.
//   LDS = 64*LSTRIDE*2 = 19,456 B -> 8 blocks/CU -> 32 waves/CU (was 16).
//   Kernel is latency-bound (MfmaUtil 5%, VALUBusy 21%, HBM 18%) -> double TLP.
// Register budget for 8 waves/EU is 64: single f32x16 acc in phase B
// (M-tile x N-tile per wave), lazy A-fragment loads, <=3 taps/thread
// (tap group == wave index, wave-uniform guards).
// lo (offsets, 18x64 fp32 = 4,608 B) aliases ls start (barrier-separated).
// grid 2048 = exactly 8/CU, id&7 = b keeps each batch on one XCD's L2.
// ---------------------------------------------------------------------------
__global__ __launch_bounds__(256, 8) void fused_kernel(const unsigned short* __restrict__ xt,
        const unsigned short* __restrict__ wobf, const float* __restrict__ b_off,
        const unsigned short* __restrict__ wbf, const float* __restrict__ bias,
        float* __restrict__ out) {
    __shared__ __align__(16) unsigned short ls[NPX * LSTRIDE];  // 19,456 B
    float* lo = (float*)ls;                     // aliased: first 4,608 B
    const int tid = threadIdx.x;
    const int id  = blockIdx.x;                 // 2048
    const int b   = id & 7;                     // batch-per-XCD heuristic
    const int rh  = id >> 3;                    // 0..255
    const int ho  = rh >> 1;
    const int p0  = (rh & 1) << 6;              // half-row origin: 0 or 64
    const int p   = tid & 63;                   // local pixel
    const int wv  = tid >> 6;                   // wave index == tap group
    const int lane = tid & 63;
    const int m    = lane & 31;
    const int kh   = lane >> 5;
    const int wo   = p0 + p;                    // global output x

    // ================= Phase A: offset conv (M=32, N=64) =================
    // Waves (0,2) and (1,3) duplicate the two N-tiles (MFMA cost trivial).
    {
        const int nbase = (wv & 1) << 5;
        f32x16 acc = {};
        for (int cc = 0; cc < 4; ++cc) {
            __syncthreads();                    // prev MFMA done with ls
            const unsigned short* xtc = xt + (size_t)(cc * B_ + b) * PLANE * 16;
            #pragma unroll
            for (int i = 0; i < 3; ++i) {
                const int t = wv + i * 4;       // wave-uniform guard
                if (t < 9) {
                    const int y  = ho - 1 + t / 3;
                    const int xx = wo - 1 + t % 3;
                    const bool ok = ((unsigned)y < (unsigned)H_) && ((unsigned)xx < (unsigned)W_);
                    bf16x8 v0 = {}, v1 = {};
                    if (ok) {
                        const unsigned short* rp = xtc + (y * W_ + xx) * 16;
                        v0 = *(const bf16x8*)rp;
                        v1 = *(const bf16x8*)(rp + 8);
                    }
                    *(bf16x8*)&ls[p * LSTRIDE + t * 16]     = v0;
                    *(bf16x8*)&ls[p * LSTRIDE + t * 16 + 8] = v1;
                }
            }
            __syncthreads();                    // ls ready
            #pragma unroll
            for (int ks = 0; ks < 9; ++ks) {
                bf16x8 a = *(const bf16x8*)&wobf[m * KTOT + cc * 144 + ks * 16 + kh * 8];
                bf16x8 s = *(const bf16x8*)&ls[(nbase + m) * LSTRIDE + ks * 16 + kh * 8];
                acc = __builtin_amdgcn_mfma_f32_32x32x16_bf16(a, s, acc, 0, 0, 0);
            }
        }
        __syncthreads();                        // MFMA reads of ls done (lo aliases ls)
        if (wv < 2) {                           // waves 2,3 are duplicates -> skip write
            #pragma unroll
            for (int r = 0; r < 16; ++r) {
                int mo = (r & 3) + ((r >> 2) << 3) + (kh << 2);
                if (mo < MOFF) lo[mo * NPX + nbase + m] = acc[r] + b_off[mo];
            }
        }
    }
    __syncthreads();                            // lo ready for phase B

    // ================= Phase B: deformable conv (M=64, N=64) =============
    const int mbase = (wv & 1) << 5;            // M tile
    const int nb0   = (wv >> 1) << 5;           // N tile

    // per-tap sample coords in regs (<=6); lo is clobbered by cc=0 staging
    float py_r[3], px_r[3];
    #pragma unroll
    for (int i = 0; i < 3; ++i) {
        const int t = wv + i * 4;
        if (t < 9) {
            py_r[i] = (float)(ho - 1 + t / 3) + lo[(2 * t) * NPX + p];
            px_r[i] = (float)(wo - 1 + t % 3) + lo[(2 * t + 1) * NPX + p];
        } else { py_r[i] = 0.f; px_r[i] = 0.f; }
    }

    f32x16 acc = {};
    for (int cc = 0; cc < 4; ++cc) {
        __syncthreads();                        // lo reads done / prev MFMA done with ls
        const unsigned short* xtc = xt + (size_t)(cc * B_ + b) * PLANE * 16;
        #pragma unroll
        for (int i = 0; i < 3; ++i) {
            const int t = wv + i * 4;           // wave-uniform guard
            if (t < 9) {
                float py = py_r[i], px = px_r[i];
                float fy = floorf(py), fx = floorf(px);
                float wy = py - fy,    wx = px - fx;
                int y0 = (int)fy, x0 = (int)fx;
                float s[16];
                #pragma unroll
                for (int j = 0; j < 16; ++j) s[j] = 0.f;
                #pragma unroll
                for (int c2 = 0; c2 < 4; ++c2) {
                    int yy = y0 + (c2 >> 1);
                    int xx = x0 + (c2 & 1);
                    bool valid = ((unsigned)yy < (unsigned)H_) && ((unsigned)xx < (unsigned)W_);
                    int yc = min(max(yy, 0), H_ - 1);
                    int xc = min(max(xx, 0), W_ - 1);
                    float wgt = ((c2 >> 1) ? wy : 1.f - wy) * ((c2 & 1) ? wx : 1.f - wx);
                    wgt = valid ? wgt : 0.f;
                    const unsigned short* rp = xtc + (yc * W_ + xc) * 16;
                    bf16x8 u0 = *(const bf16x8*)rp;
                    bf16x8 u1 = *(const bf16x8*)(rp + 8);
                    #pragma unroll
                    for (int j = 0; j < 8; ++j) {
                        s[j]     += wgt * bf2f(u0[j]);
                        s[8 + j] += wgt * bf2f(u1[j]);
                    }
                }
                bf16x8 v0, v1;
                #pragma unroll
                for (int j = 0; j < 8; ++j) {
                    v0[j] = (short)f2bf(s[j]);
                    v1[j] = (short)f2bf(s[8 + j]);
                }
                *(bf16x8*)&ls[p * LSTRIDE + t * 16]     = v0;
                *(bf16x8*)&ls[p * LSTRIDE + t * 16 + 8] = v1;
            }
        }
        __syncthreads();                        // ls ready
        // MFMA: A-fragments loaded lazily (L2-hot wbf)
        #pragma unroll
        for (int ks = 0; ks < 9; ++ks) {
            bf16x8 a  = *(const bf16x8*)&wbf[(mbase + m) * KTOT + cc * 144 + ks * 16 + kh * 8];
            bf16x8 s0 = *(const bf16x8*)&ls[(nb0 + m) * LSTRIDE + ks * 16 + kh * 8];
            acc = __builtin_amdgcn_mfma_f32_32x32x16_bf16(a, s0, acc, 0, 0, 0);
        }
    }

    // epilogue: D col = pixel (global p0+nb0+m), row = out channel
    {
        const int colg = p0 + nb0 + m;
        float* op = out + (size_t)b * O_ * PLANE + ho * WO_ + colg;
        #pragma unroll
        for (int r = 0; r < 16; ++r) {
            int mo = mbase + (r & 3) + ((r >> 2) << 3) + (kh << 2);
            __builtin_nontemporal_store(acc[r] + bias[mo], op + (size_t)mo * PLANE);
        }
    }
}

// ---------------------------------------------------------------------------
extern "C" void kernel_launch(void* const* d_in, const int* in_sizes, int n_in,
                              void* d_out, int out_size, void* d_ws, size_t ws_size,
                              hipStream_t stream) {
    const float* x     = (const float*)d_in[0];
    const float* w_off = (const float*)d_in[1];
    const float* b_off = (const float*)d_in[2];
    const float* w     = (const float*)d_in[3];
    const float* bias  = (const float*)d_in[4];
    float* out = (float*)d_out;

    unsigned short* wbf  = (unsigned short*)d_ws;                   // 72 KB (tap-major)
    unsigned short* wobf = wbf + O_ * KTOT;                         // 36 KB (tap-major)
    unsigned short* xt   = wobf + 32 * KTOT;                        // 16.78 MB chunk-major

    cvt_all_kernel<<<(96 * KTOT + 255) / 256, 256, 0, stream>>>(w, w_off, wbf);
    nhwc_kernel   <<<B_ * H_, 256, 0, stream>>>(x, xt);
    fused_kernel  <<<B_ * HO_ * 2, 256, 0, stream>>>(xt, wobf, b_off, wbf, bias, out);
}

// Round 2
// 227.941 us; speedup vs baseline: 1.1440x; 1.1440x over previous
//
#include <hip/hip_runtime.h>

// Problem constants (fixed by setup_inputs)
#define B_   8
#define C_   64
#define O_   64
#define H_   128
#define W_   128
#define HO_  128
#define WO_  128
#define K2_  9
#define MOFF 18          // 2*K*K offset channels
#define PLANE (H_*W_)    // 16384
#define KTOT 576         // C_*K2_
// LDS row stride in bf16 units: 304 B = 19 x 16B groups. Group stride 19 mod 32
// (odd) -> b128 ops across consecutive rows are conflict-free (measured 0 conflicts).
#define LSTRIDE 152

typedef short bf16x8 __attribute__((ext_vector_type(8)));
typedef float f32x16 __attribute__((ext_vector_type(16)));

__device__ __forceinline__ unsigned short f2bf(float f) {
    // round-to-nearest-even fp32 -> bf16
    unsigned u = __float_as_uint(f);
    u += 0x7fff + ((u >> 16) & 1);
    return (unsigned short)(u >> 16);
}
__device__ __forceinline__ float bf2f(short v) {
    return __uint_as_float(((unsigned)(unsigned short)v) << 16);
}

// ---------------------------------------------------------------------------
// PREP (merged): blocks < 1024 do the NHWC transpose; blocks >= 1024 convert
// both weight tensors to bf16 TAP-MAJOR rows:
//   pos = cc*144 + t*16 + cl  <->  w[o][c = cc*16+cl][tap t]
//   rows 0..63  -> main conv (wbf); rows 64..95 -> offset conv (o>=18 zero)
// xt layout (chunk-major NHWC):
//   xt[((cc*B + b)*PLANE + y*W + px)*16 + cl] = bf16(x[((b*64+cc*16+cl)*H+y)*W+px])
// ---------------------------------------------------------------------------
__global__ __launch_bounds__(256) void prep_kernel(const float* __restrict__ x,
                                                   const float* __restrict__ w,
                                                   const float* __restrict__ w_off,
                                                   unsigned short* __restrict__ xt,
                                                   unsigned short* __restrict__ wbf) {
    __shared__ unsigned short T[64 * 130];      // stride 130 (odd 16B groups)
    const int tid = threadIdx.x;
    if (blockIdx.x >= B_ * H_) {                // ---- weight conversion ----
        int i = (blockIdx.x - B_ * H_) * 256 + tid;   // 96*576 = 55296
        if (i < 96 * KTOT) {
            int o = i / KTOT, pos = i % KTOT;
            int cc = pos / 144, r = pos % 144, t = r / 16, cl = r % 16;
            int c = cc * 16 + cl;
            unsigned short v;
            if (o < O_)             v = f2bf(w[o * KTOT + c * 9 + t]);
            else if (o < O_ + MOFF) v = f2bf(w_off[(o - O_) * KTOT + c * 9 + t]);
            else                    v = 0;
            wbf[i] = v;
        }
        return;
    }
    // ---- NHWC transpose ----
    const int b = blockIdx.x & 7;
    const int y = blockIdx.x >> 3;
    const float* src = x + (size_t)b * C_ * PLANE + y * W_;
    for (int i = tid; i < 64 * 128; i += 256) {
        int c = i >> 7, px = i & 127;
        T[c * 130 + px] = f2bf(src[c * PLANE + px]);
    }
    __syncthreads();
    for (int j = tid; j < 128 * 4; j += 256) {
        int cc = j >> 7, px = j & 127;
        unsigned short* dst = xt + ((size_t)(cc * B_ + b) * PLANE + y * W_ + px) * 16;
        ushort4 v0 = { T[(cc*16+ 0)*130+px], T[(cc*16+ 1)*130+px],
                       T[(cc*16+ 2)*130+px], T[(cc*16+ 3)*130+px] };
        ushort4 v1 = { T[(cc*16+ 4)*130+px], T[(cc*16+ 5)*130+px],
                       T[(cc*16+ 6)*130+px], T[(cc*16+ 7)*130+px] };
        ushort4 v2 = { T[(cc*16+ 8)*130+px], T[(cc*16+ 9)*130+px],
                       T[(cc*16+10)*130+px], T[(cc*16+11)*130+px] };
        ushort4 v3 = { T[(cc*16+12)*130+px], T[(cc*16+13)*130+px],
                       T[(cc*16+14)*130+px], T[(cc*16+15)*130+px] };
        *(ushort4*)(dst)      = v0;
        *(ushort4*)(dst + 4)  = v1;
        *(ushort4*)(dst + 8)  = v2;
        *(ushort4*)(dst + 12) = v3;
    }
}

// ---------------------------------------------------------------------------
// FUSED offset-conv + deformable-conv (R11).
// Block = (b,ho), 512 threads = 8 waves, N = 128 pixels (full row).
//   LDS 38,912 B -> 4 blocks/CU (LDS cap); 8 waves/block -> 32 waves/CU (100%).
//   grid 1024 = exactly 4/CU, zero tail. __launch_bounds__(512,8): 64-reg total.
// R10 post-mortem: the 64-reg total budget spilled (FETCH/WRITE doubled) because
// the full-16-channel sampler needs ~50 arch regs. Fix here: HALF-SPLIT sampling
// (8 channels at a time: s[8] + one 16B load per corner-half) + <=3 taps/thread
// (4 tap groups) + one 32x32 MFMA tile per wave (single f32x16 acc in AGPRs).
// lo (offsets, 18x128 fp32 = 9,216 B) aliases ls start (barrier-separated).
// ---------------------------------------------------------------------------
__global__ __launch_bounds__(512, 8) void fused_kernel(const unsigned short* __restrict__ xt,
        const unsigned short* __restrict__ wobf, const float* __restrict__ b_off,
        const unsigned short* __restrict__ wbf, const float* __restrict__ bias,
        float* __restrict__ out) {
    __shared__ __align__(16) unsigned short ls[128 * LSTRIDE];  // 38,912 B
    float* lo = (float*)ls;                     // aliased: first 9,216 B
    const int tid = threadIdx.x;
    const int id  = blockIdx.x;                 // 1024
    const int b   = id & 7;                     // batch-per-XCD heuristic
    const int ho  = id >> 3;
    const int p   = tid & 127;                  // pixel = wo
    const int sub = tid >> 7;                   // tap group 0..3 (wave-uniform)
    const int wv  = tid >> 6;                   // wave 0..7
    const int lane = tid & 63;
    const int m    = lane & 31;
    const int kh   = lane >> 5;

    // ================= Phase A: offset conv (M=32, N=128) =================
    // Staging: all 8 waves. MFMA + epilogue: waves 0..3 only (one N-tile each).
    {
        const int nbase = (wv & 3) << 5;
        f32x16 acc = {};
        for (int cc = 0; cc < 4; ++cc) {
            __syncthreads();                    // prev MFMA done with ls
            const unsigned short* xtc = xt + (size_t)(cc * B_ + b) * PLANE * 16;
            #pragma unroll
            for (int i = 0; i < 3; ++i) {
                const int t = sub + i * 4;      // wave-uniform guard
                if (t < 9) {
                    const int y  = ho - 1 + t / 3;
                    const int xx = p  - 1 + t % 3;
                    const bool ok = ((unsigned)y < (unsigned)H_) && ((unsigned)xx < (unsigned)W_);
                    bf16x8 v0 = {}, v1 = {};
                    if (ok) {
                        const unsigned short* rp = xtc + (y * W_ + xx) * 16;
                        v0 = *(const bf16x8*)rp;
                        v1 = *(const bf16x8*)(rp + 8);
                    }
                    *(bf16x8*)&ls[p * LSTRIDE + t * 16]     = v0;
                    *(bf16x8*)&ls[p * LSTRIDE + t * 16 + 8] = v1;
                }
            }
            __syncthreads();                    // ls ready
            if (wv < 4) {
                #pragma unroll
                for (int ks = 0; ks < 9; ++ks) {
                    bf16x8 a = *(const bf16x8*)&wobf[m * KTOT + cc * 144 + ks * 16 + kh * 8];
                    bf16x8 s = *(const bf16x8*)&ls[(nbase + m) * LSTRIDE + ks * 16 + kh * 8];
                    acc = __builtin_amdgcn_mfma_f32_32x32x16_bf16(a, s, acc, 0, 0, 0);
                }
            }
        }
        __syncthreads();                        // MFMA reads of ls done (lo aliases ls)
        if (wv < 4) {
            #pragma unroll
            for (int r = 0; r < 16; ++r) {
                int mo = (r & 3) + ((r >> 2) << 3) + (kh << 2);
                if (mo < MOFF) lo[mo * 128 + nbase + m] = acc[r] + b_off[mo];
            }
        }
    }
    __syncthreads();                            // lo ready for phase B

    // ================= Phase B: deformable conv (M=64, N=128) =============
    const int mbase = (wv & 1) << 5;            // M tile: 0/32
    const int nb0   = (wv >> 1) << 5;           // N tile: 0/32/64/96

    // per-tap sample coords only (<=6 regs); lo clobbered by cc=0 staging
    float py_r[3], px_r[3];
    #pragma unroll
    for (int i = 0; i < 3; ++i) {
        const int t = sub + i * 4;
        if (t < 9) {
            py_r[i] = (float)(ho - 1 + t / 3) + lo[(2 * t) * 128 + p];
            px_r[i] = (float)(p  - 1 + t % 3) + lo[(2 * t + 1) * 128 + p];
        } else { py_r[i] = 0.f; px_r[i] = 0.f; }
    }

    f32x16 acc = {};
    for (int cc = 0; cc < 4; ++cc) {
        __syncthreads();                        // lo reads done / prev MFMA done with ls
        const unsigned short* xtc = xt + (size_t)(cc * B_ + b) * PLANE * 16;
        #pragma unroll
        for (int i = 0; i < 3; ++i) {
            const int t = sub + i * 4;          // wave-uniform guard
            if (t < 9) {
                float py = py_r[i], px = px_r[i];
                float fy = floorf(py), fx = floorf(px);
                float wy = py - fy,    wx = px - fx;
                int y0 = (int)fy, x0 = (int)fx;
                // half-split sampling: 8 channels at a time (peak live ~= s8+u+coords)
                #pragma unroll
                for (int h = 0; h < 2; ++h) {
                    float s8[8];
                    #pragma unroll
                    for (int j = 0; j < 8; ++j) s8[j] = 0.f;
                    #pragma unroll
                    for (int c2 = 0; c2 < 4; ++c2) {
                        int yy = y0 + (c2 >> 1);
                        int xx = x0 + (c2 & 1);
                        bool valid = ((unsigned)yy < (unsigned)H_) && ((unsigned)xx < (unsigned)W_);
                        int yc = min(max(yy, 0), H_ - 1);
                        int xc = min(max(xx, 0), W_ - 1);
                        float wgt = ((c2 >> 1) ? wy : 1.f - wy) * ((c2 & 1) ? wx : 1.f - wx);
                        wgt = valid ? wgt : 0.f;
                        const unsigned short* rp = xtc + (yc * W_ + xc) * 16 + h * 8;
                        bf16x8 u = *(const bf16x8*)rp;
                        #pragma unroll
                        for (int j = 0; j < 8; ++j) s8[j] += wgt * bf2f(u[j]);
                    }
                    bf16x8 v;
                    #pragma unroll
                    for (int j = 0; j < 8; ++j) v[j] = (short)f2bf(s8[j]);
                    *(bf16x8*)&ls[p * LSTRIDE + t * 16 + h * 8] = v;
                }
            }
        }
        __syncthreads();                        // ls ready
        // MFMA: one 32x32 tile per wave; A-fragments lazy (L2-hot wbf)
        #pragma unroll
        for (int ks = 0; ks < 9; ++ks) {
            bf16x8 a  = *(const bf16x8*)&wbf[(mbase + m) * KTOT + cc * 144 + ks * 16 + kh * 8];
            bf16x8 s0 = *(const bf16x8*)&ls[(nb0 + m) * LSTRIDE + ks * 16 + kh * 8];
            acc = __builtin_amdgcn_mfma_f32_32x32x16_bf16(a, s0, acc, 0, 0, 0);
        }
    }

    // epilogue: D col = pixel (nb0+m), row = out channel (mbase+...)
    {
        const int colg = nb0 + m;
        float* op = out + (size_t)b * O_ * PLANE + ho * WO_ + colg;
        #pragma unroll
        for (int r = 0; r < 16; ++r) {
            int mo = mbase + (r & 3) + ((r >> 2) << 3) + (kh << 2);
            __builtin_nontemporal_store(acc[r] + bias[mo], op + (size_t)mo * PLANE);
        }
    }
}

// ---------------------------------------------------------------------------
extern "C" void kernel_launch(void* const* d_in, const int* in_sizes, int n_in,
                              void* d_out, int out_size, void* d_ws, size_t ws_size,
                              hipStream_t stream) {
    const float* x     = (const float*)d_in[0];
    const float* w_off = (const float*)d_in[1];
    const float* b_off = (const float*)d_in[2];
    const float* w     = (const float*)d_in[3];
    const float* bias  = (const float*)d_in[4];
    float* out = (float*)d_out;

    unsigned short* wbf  = (unsigned short*)d_ws;                   // 72 KB (tap-major)
    unsigned short* wobf = wbf + O_ * KTOT;                         // 36 KB (tap-major)
    unsigned short* xt   = wobf + 32 * KTOT;                        // 16.78 MB chunk-major

    const int wblocks = (96 * KTOT + 255) / 256;                    // 216
    prep_kernel <<<B_ * H_ + wblocks, 256, 0, stream>>>(x, w, w_off, xt, wbf);
    fused_kernel<<<B_ * HO_, 512, 0, stream>>>(xt, wobf, b_off, wbf, bias, out);
}

// Round 3
// 206.677 us; speedup vs baseline: 1.2617x; 1.1029x over previous
//
#include <hip/hip_runtime.h>

// Problem constants (fixed by setup_inputs)
#define B_   8
#define C_   64
#define O_   64
#define H_   128
#define W_   128
#define HO_  128
#define WO_  128
#define K2_  9
#define MOFF 18          // 2*K*K offset channels
#define PLANE (H_*W_)    // 16384
#define KTOT 576         // C_*K2_
// LDS row stride in bf16 units: 304 B = 19 x 16B groups. Group stride 19 mod 32
// (odd) -> b128 ops across consecutive rows are conflict-free (measured 0 conflicts).
#define LSTRIDE 152

typedef short bf16x8 __attribute__((ext_vector_type(8)));
typedef float f32x16 __attribute__((ext_vector_type(16)));

__device__ __forceinline__ unsigned short f2bf(float f) {
    // round-to-nearest-even fp32 -> bf16
    unsigned u = __float_as_uint(f);
    u += 0x7fff + ((u >> 16) & 1);
    return (unsigned short)(u >> 16);
}
__device__ __forceinline__ float bf2f(short v) {
    return __uint_as_float(((unsigned)(unsigned short)v) << 16);
}

// ---------------------------------------------------------------------------
// PREP (merged): blocks < 1024 do the NHWC transpose; blocks >= 1024 convert
// both weight tensors to bf16 TAP-MAJOR rows:
//   pos = cc*144 + t*16 + cl  <->  w[o][c = cc*16+cl][tap t]
//   rows 0..63  -> main conv (wbf); rows 64..95 -> offset conv (o>=18 zero)
// xt layout (chunk-major NHWC):
//   xt[((cc*B + b)*PLANE + y*W + px)*16 + cl] = bf16(x[((b*64+cc*16+cl)*H+y)*W+px])
// ---------------------------------------------------------------------------
__global__ __launch_bounds__(256) void prep_kernel(const float* __restrict__ x,
                                                   const float* __restrict__ w,
                                                   const float* __restrict__ w_off,
                                                   unsigned short* __restrict__ xt,
                                                   unsigned short* __restrict__ wbf) {
    __shared__ unsigned short T[64 * 130];      // stride 130 (odd 16B groups)
    const int tid = threadIdx.x;
    if (blockIdx.x >= B_ * H_) {                // ---- weight conversion ----
        int i = (blockIdx.x - B_ * H_) * 256 + tid;   // 96*576 = 55296
        if (i < 96 * KTOT) {
            int o = i / KTOT, pos = i % KTOT;
            int cc = pos / 144, r = pos % 144, t = r / 16, cl = r % 16;
            int c = cc * 16 + cl;
            unsigned short v;
            if (o < O_)             v = f2bf(w[o * KTOT + c * 9 + t]);
            else if (o < O_ + MOFF) v = f2bf(w_off[(o - O_) * KTOT + c * 9 + t]);
            else                    v = 0;
            wbf[i] = v;
        }
        return;
    }
    // ---- NHWC transpose ----
    const int b = blockIdx.x & 7;
    const int y = blockIdx.x >> 3;
    const float* src = x + (size_t)b * C_ * PLANE + y * W_;
    for (int i = tid; i < 64 * 128; i += 256) {
        int c = i >> 7, px = i & 127;
        T[c * 130 + px] = f2bf(src[c * PLANE + px]);
    }
    __syncthreads();
    for (int j = tid; j < 128 * 4; j += 256) {
        int cc = j >> 7, px = j & 127;
        unsigned short* dst = xt + ((size_t)(cc * B_ + b) * PLANE + y * W_ + px) * 16;
        ushort4 v0 = { T[(cc*16+ 0)*130+px], T[(cc*16+ 1)*130+px],
                       T[(cc*16+ 2)*130+px], T[(cc*16+ 3)*130+px] };
        ushort4 v1 = { T[(cc*16+ 4)*130+px], T[(cc*16+ 5)*130+px],
                       T[(cc*16+ 6)*130+px], T[(cc*16+ 7)*130+px] };
        ushort4 v2 = { T[(cc*16+ 8)*130+px], T[(cc*16+ 9)*130+px],
                       T[(cc*16+10)*130+px], T[(cc*16+11)*130+px] };
        ushort4 v3 = { T[(cc*16+12)*130+px], T[(cc*16+13)*130+px],
                       T[(cc*16+14)*130+px], T[(cc*16+15)*130+px] };
        *(ushort4*)(dst)      = v0;
        *(ushort4*)(dst + 4)  = v1;
        *(ushort4*)(dst + 8)  = v2;
        *(ushort4*)(dst + 12) = v3;
    }
}

// ---------------------------------------------------------------------------
// FUSED offset-conv + deformable-conv (R12): WAVE-PRIVATE, ZERO BARRIERS.
// Block = (b,ho), 256 threads = 4 waves. Each wave owns a 32-pixel N-tile:
//   - stages samples for ITS pixels into ITS private LDS region (9,728 B)
//   - MFMAs from its own region only (B-op n = lane&31 = its pixel)
//   - phase A offsets land in the producing wave (D col = pixel); the kh-half
//     exchange goes through the private region too
// => no inter-wave dependency => NO __syncthreads anywhere. Waves drift apart;
// one wave's gather latency hides under another's MFMA/VALU on the same SIMD
// (the barrier drain was the exposed-latency mechanism in R9's 113 us).
// Correctness: per-wave DS ops execute in order (FIFO pipe), so stage-write ->
// fragment-read RAW inside one wave needs only the compiler's lgkmcnt.
// Tap split: lanes kh=0 handle taps 0..4, kh=1 taps 5..8 (t = kh*5 + i).
// Budget: __launch_bounds__(256,4) = 128 regs/wave (R10/R11 post-mortem: the
// sampler spills below that; R9 proved it fits here). LDS 38,912 B -> 4
// blocks/CU, grid 1024 = exactly 4/CU, zero tail.
// ---------------------------------------------------------------------------
__global__ __launch_bounds__(256, 4) void fused_kernel(const unsigned short* __restrict__ xt,
        const unsigned short* __restrict__ wobf, const float* __restrict__ b_off,
        const unsigned short* __restrict__ wbf, const float* __restrict__ bias,
        float* __restrict__ out) {
    __shared__ __align__(16) unsigned short ls[4 * 32 * LSTRIDE];  // 38,912 B
    const int tid  = threadIdx.x;
    const int id   = blockIdx.x;                // 1024
    const int b    = id & 7;                    // batch-per-XCD heuristic
    const int ho   = id >> 3;
    const int wv   = tid >> 6;                  // wave 0..3
    const int lane = tid & 63;
    const int m    = lane & 31;                 // local pixel within wave tile
    const int kh   = lane >> 5;                 // K-half AND tap-set selector
    const int wo   = (wv << 5) + m;             // global output x
    unsigned short* lsw = ls + wv * 32 * LSTRIDE;   // wave-private region
    float* low = (float*)lsw;                   // aliased offset buf [18][32]

    // ================= Phase A: offset conv (per-wave M=32, N=32) ==========
    f32x16 acc0 = {};
    for (int cc = 0; cc < 4; ++cc) {
        const unsigned short* xtc = xt + (size_t)(cc * B_ + b) * PLANE * 16;
        #pragma unroll
        for (int i = 0; i < 5; ++i) {
            if (!kh || i < 4) {                 // kh=0: taps 0..4, kh=1: taps 5..8
                const int t  = kh * 5 + i;
                const int y  = ho - 1 + t / 3;
                const int xx = wo - 1 + t % 3;
                const bool ok = ((unsigned)y < (unsigned)H_) && ((unsigned)xx < (unsigned)W_);
                bf16x8 v0 = {}, v1 = {};
                if (ok) {
                    const unsigned short* rp = xtc + (y * W_ + xx) * 16;
                    v0 = *(const bf16x8*)rp;
                    v1 = *(const bf16x8*)(rp + 8);
                }
                *(bf16x8*)&lsw[m * LSTRIDE + t * 16]     = v0;
                *(bf16x8*)&lsw[m * LSTRIDE + t * 16 + 8] = v1;
            }
        }
        // per-wave in-order DS pipe: reads below see the writes above
        #pragma unroll
        for (int ks = 0; ks < 9; ++ks) {
            bf16x8 a = *(const bf16x8*)&wobf[m * KTOT + cc * 144 + ks * 16 + kh * 8];
            bf16x8 s = *(const bf16x8*)&lsw[m * LSTRIDE + ks * 16 + kh * 8];
            acc0 = __builtin_amdgcn_mfma_f32_32x32x16_bf16(a, s, acc0, 0, 0, 0);
        }
    }
    // offsets -> private low[mo][m]; then each lane picks up its taps' (dy,dx)
    #pragma unroll
    for (int r = 0; r < 16; ++r) {
        int mo = (r & 3) + ((r >> 2) << 3) + (kh << 2);
        if (mo < MOFF) low[mo * 32 + m] = acc0[r] + b_off[mo];
    }
    float py_r[5], px_r[5];
    #pragma unroll
    for (int i = 0; i < 5; ++i) {
        if (!kh || i < 4) {
            const int t = kh * 5 + i;
            py_r[i] = (float)(ho - 1 + t / 3) + low[(2 * t) * 32 + m];
            px_r[i] = (float)(wo - 1 + t % 3) + low[(2 * t + 1) * 32 + m];
        }
    }

    // ================= Phase B: deformable conv (per-wave M=64, N=32) ======
    f32x16 acc[2] = {};
    for (int cc = 0; cc < 4; ++cc) {
        const unsigned short* xtc = xt + (size_t)(cc * B_ + b) * PLANE * 16;
        #pragma unroll
        for (int i = 0; i < 5; ++i) {
            if (!kh || i < 4) {
                const int t = kh * 5 + i;
                float py = py_r[i], px = px_r[i];
                float fy = floorf(py), fx = floorf(px);
                float wy = py - fy,    wx = px - fx;
                int y0 = (int)fy, x0 = (int)fx;
                float s[16];
                #pragma unroll
                for (int j = 0; j < 16; ++j) s[j] = 0.f;
                #pragma unroll
                for (int c2 = 0; c2 < 4; ++c2) {
                    int yy = y0 + (c2 >> 1);
                    int xx = x0 + (c2 & 1);
                    bool valid = ((unsigned)yy < (unsigned)H_) && ((unsigned)xx < (unsigned)W_);
                    int yc = min(max(yy, 0), H_ - 1);
                    int xc = min(max(xx, 0), W_ - 1);
                    float wgt = ((c2 >> 1) ? wy : 1.f - wy) * ((c2 & 1) ? wx : 1.f - wx);
                    wgt = valid ? wgt : 0.f;
                    const unsigned short* rp = xtc + (yc * W_ + xc) * 16;
                    bf16x8 u0 = *(const bf16x8*)rp;
                    bf16x8 u1 = *(const bf16x8*)(rp + 8);
                    #pragma unroll
                    for (int j = 0; j < 8; ++j) {
                        s[j]     += wgt * bf2f(u0[j]);
                        s[8 + j] += wgt * bf2f(u1[j]);
                    }
                }
                bf16x8 v0, v1;
                #pragma unroll
                for (int j = 0; j < 8; ++j) {
                    v0[j] = (short)f2bf(s[j]);
                    v1[j] = (short)f2bf(s[8 + j]);
                }
                *(bf16x8*)&lsw[m * LSTRIDE + t * 16]     = v0;
                *(bf16x8*)&lsw[m * LSTRIDE + t * 16 + 8] = v1;
            }
        }
        // MFMA over own tile; A-fragments lazy (L2-hot wbf); M=64 via acc[2]
        #pragma unroll
        for (int ks = 0; ks < 9; ++ks) {
            bf16x8 b0 = *(const bf16x8*)&lsw[m * LSTRIDE + ks * 16 + kh * 8];
            bf16x8 a0 = *(const bf16x8*)&wbf[m * KTOT + cc * 144 + ks * 16 + kh * 8];
            bf16x8 a1 = *(const bf16x8*)&wbf[(32 + m) * KTOT + cc * 144 + ks * 16 + kh * 8];
            acc[0] = __builtin_amdgcn_mfma_f32_32x32x16_bf16(a0, b0, acc[0], 0, 0, 0);
            acc[1] = __builtin_amdgcn_mfma_f32_32x32x16_bf16(a1, b0, acc[1], 0, 0, 0);
        }
    }

    // epilogue: D col = pixel (wo), row = out channel (+32 for acc[1])
    {
        float* op = out + (size_t)b * O_ * PLANE + ho * WO_ + wo;
        #pragma unroll
        for (int nt = 0; nt < 2; ++nt) {
            #pragma unroll
            for (int r = 0; r < 16; ++r) {
                int mo = (nt << 5) + (r & 3) + ((r >> 2) << 3) + (kh << 2);
                __builtin_nontemporal_store(acc[nt][r] + bias[mo], op + (size_t)mo * PLANE);
            }
        }
    }
}

// ---------------------------------------------------------------------------
extern "C" void kernel_launch(void* const* d_in, const int* in_sizes, int n_in,
                              void* d_out, int out_size, void* d_ws, size_t ws_size,
                              hipStream_t stream) {
    const float* x     = (const float*)d_in[0];
    const float* w_off = (const float*)d_in[1];
    const float* b_off = (const float*)d_in[2];
    const float* w     = (const float*)d_in[3];
    const float* bias  = (const float*)d_in[4];
    float* out = (float*)d_out;

    unsigned short* wbf  = (unsigned short*)d_ws;                   // 72 KB (tap-major)
    unsigned short* wobf = wbf + O_ * KTOT;                         // 36 KB (tap-major)
    unsigned short* xt   = wobf + 32 * KTOT;                        // 16.78 MB chunk-major

    const int wblocks = (96 * KTOT + 255) / 256;                    // 216
    prep_kernel <<<B_ * H_ + wblocks, 256, 0, stream>>>(x, w, w_off, xt, wbf);
    fused_kernel<<<B_ * HO_, 256, 0, stream>>>(xt, wobf, b_off, wbf, bias, out);
}

// Round 4
// 145.234 us; speedup vs baseline: 1.7955x; 1.4231x over previous
//
#include <hip/hip_runtime.h>

// Problem constants (fixed by setup_inputs)
#define B_   8
#define C_   64
#define O_   64
#define H_   128
#define W_   128
#define HO_  128
#define WO_  128
#define K2_  9
#define MOFF 18          // 2*K*K offset channels
#define PLANE (H_*W_)    // 16384
#define KTOT 576         // C_*K2_

// Row-band geometry (R13): rows ho-2..ho+2, cols -2..129 (zero-padded).
// Two planes (kh = channel half), each [5][132] cells of 16B (8 bf16).
#define BROWS 5
#define BCOLS 132
#define PSTRIDE (BROWS*BCOLS*8)   // 5280 ushorts = 10,560 B per plane

typedef short bf16x8 __attribute__((ext_vector_type(8)));
typedef float f32x16 __attribute__((ext_vector_type(16)));

__device__ __forceinline__ unsigned short f2bf(float f) {
    // round-to-nearest-even fp32 -> bf16
    unsigned u = __float_as_uint(f);
    u += 0x7fff + ((u >> 16) & 1);
    return (unsigned short)(u >> 16);
}
__device__ __forceinline__ float bf2f(short v) {
    return __uint_as_float(((unsigned)(unsigned short)v) << 16);
}

// ---------------------------------------------------------------------------
// PREP (merged): blocks < 1024 do the NHWC transpose; blocks >= 1024 convert
// both weight tensors to bf16 TAP-MAJOR rows:
//   pos = cc*144 + t*16 + cl  <->  w[o][c = cc*16+cl][tap t]
//   rows 0..63  -> main conv (wbf); rows 64..95 -> offset conv (o>=18 zero)
// xt layout (chunk-major NHWC):
//   xt[((cc*B + b)*PLANE + y*W + px)*16 + cl] = bf16(x[((b*64+cc*16+cl)*H+y)*W+px])
// ---------------------------------------------------------------------------
__global__ __launch_bounds__(256) void prep_kernel(const float* __restrict__ x,
                                                   const float* __restrict__ w,
                                                   const float* __restrict__ w_off,
                                                   unsigned short* __restrict__ xt,
                                                   unsigned short* __restrict__ wbf) {
    __shared__ unsigned short T[64 * 130];      // stride 130 (odd 16B groups)
    const int tid = threadIdx.x;
    if (blockIdx.x >= B_ * H_) {                // ---- weight conversion ----
        int i = (blockIdx.x - B_ * H_) * 256 + tid;   // 96*576 = 55296
        if (i < 96 * KTOT) {
            int o = i / KTOT, pos = i % KTOT;
            int cc = pos / 144, r = pos % 144, t = r / 16, cl = r % 16;
            int c = cc * 16 + cl;
            unsigned short v;
            if (o < O_)             v = f2bf(w[o * KTOT + c * 9 + t]);
            else if (o < O_ + MOFF) v = f2bf(w_off[(o - O_) * KTOT + c * 9 + t]);
            else                    v = 0;
            wbf[i] = v;
        }
        return;
    }
    // ---- NHWC transpose ----
    const int b = blockIdx.x & 7;
    const int y = blockIdx.x >> 3;
    const float* src = x + (size_t)b * C_ * PLANE + y * W_;
    for (int i = tid; i < 64 * 128; i += 256) {
        int c = i >> 7, px = i & 127;
        T[c * 130 + px] = f2bf(src[c * PLANE + px]);
    }
    __syncthreads();
    for (int j = tid; j < 128 * 4; j += 256) {
        int cc = j >> 7, px = j & 127;
        unsigned short* dst = xt + ((size_t)(cc * B_ + b) * PLANE + y * W_ + px) * 16;
        ushort4 v0 = { T[(cc*16+ 0)*130+px], T[(cc*16+ 1)*130+px],
                       T[(cc*16+ 2)*130+px], T[(cc*16+ 3)*130+px] };
        ushort4 v1 = { T[(cc*16+ 4)*130+px], T[(cc*16+ 5)*130+px],
                       T[(cc*16+ 6)*130+px], T[(cc*16+ 7)*130+px] };
        ushort4 v2 = { T[(cc*16+ 8)*130+px], T[(cc*16+ 9)*130+px],
                       T[(cc*16+10)*130+px], T[(cc*16+11)*130+px] };
        ushort4 v3 = { T[(cc*16+12)*130+px], T[(cc*16+13)*130+px],
                       T[(cc*16+14)*130+px], T[(cc*16+15)*130+px] };
        *(ushort4*)(dst)      = v0;
        *(ushort4*)(dst + 4)  = v1;
        *(ushort4*)(dst + 8)  = v2;
        *(ushort4*)(dst + 12) = v3;
    }
}

// ---------------------------------------------------------------------------
// FUSED offset-conv + deformable-conv (R13): LDS ROW-BAND, NO SCATTERED GATHERS.
// Block = (b,ho), 256 threads = 4 waves. Per cc-chunk, stage a 5-row input
// band (rows ho-2..ho+2, cols -2..129 zero-padded, 2 kh-planes of [5][132]x16B)
// into LDS with fully-coalesced 32B streaming loads (one vmcnt drain), then:
//   Phase A: MFMA B-fragments are DIRECT ds_read_b128 from the band (taps are
//            regular-grid). The whole tap-staging buffer is deleted.
//   Phase B: each lane (m,kh) blends 4 band corners (4x ds_read_b128, ~120cy
//            pipelined LDS latency instead of 200-900cy L2/HBM) into its
//            B-fragment in-register, feeding MFMA directly. No ls either.
// Out-of-band offsets (|off|>=1, P~1e-4/tap on this data) take an exec-masked
// slow path replaying the exact global-gather math -> correct for ANY offset.
// Decomposition: wave owns px tile [wv*32, wv*32+32); phase A M=32/N=32,
// phase B M=64 (acc[2]) / N=32. Same verified MFMA layouts as R9/R12.
// LDS = 21,120(band) + 9,216(lo) = 30,336 B; occupancy reg-capped ~4 blk/CU.
// ---------------------------------------------------------------------------
__global__ __launch_bounds__(256, 4) void fused_kernel(const unsigned short* __restrict__ xt,
        const unsigned short* __restrict__ wobf, const float* __restrict__ b_off,
        const unsigned short* __restrict__ wbf, const float* __restrict__ bias,
        float* __restrict__ out) {
    __shared__ __align__(16) unsigned short band[2 * PSTRIDE];   // 21,120 B
    __shared__ float lo[MOFF * 128];                             // 9,216 B
    const int tid  = threadIdx.x;
    const int id   = blockIdx.x;                // 1024
    const int b    = id & 7;                    // batch-per-XCD heuristic
    const int ho   = id >> 3;
    const int wv   = tid >> 6;                  // wave 0..3
    const int lane = tid & 63;
    const int m    = lane & 31;
    const int kh   = lane >> 5;                 // channel half
    const int pxg  = (wv << 5) + m;             // owned output pixel

    // Coalesced band staging: position j=(r,c); thread loads 32B (16 ch) and
    // writes 16B to each plane. Consecutive threads read consecutive 32B.
    auto stage = [&](const unsigned short* xtc, int r0, int nrows) {
        const int npos = nrows * BCOLS;
        uint4 va[3], vb[3];
        #pragma unroll
        for (int it = 0; it < 3; ++it) {        // issue all loads first (T14)
            va[it] = (uint4){0, 0, 0, 0};
            vb[it] = (uint4){0, 0, 0, 0};
            int j = tid + it * 256;
            if (j < npos) {
                int r = j / BCOLS, c = j - r * BCOLS;
                int y = ho - 2 + r0 + r, x = c - 2;
                if (((unsigned)y < (unsigned)H_) && ((unsigned)x < (unsigned)W_)) {
                    const uint4* gp = (const uint4*)(xtc + (y * W_ + x) * 16);
                    va[it] = gp[0];
                    vb[it] = gp[1];
                }
            }
        }
        #pragma unroll
        for (int it = 0; it < 3; ++it) {
            int j = tid + it * 256;
            if (j < npos) {
                int r = j / BCOLS, c = j - r * BCOLS;
                int s = ((r0 + r) * BCOLS + c) * 8;
                *(uint4*)&band[s]           = va[it];
                *(uint4*)&band[PSTRIDE + s] = vb[it];
            }
        }
    };

    // ================= Phase A: offset conv (per-wave M=32, N=32) ==========
    f32x16 acc0 = {};
    for (int cc = 0; cc < 4; ++cc) {
        const unsigned short* xtc = xt + (size_t)(cc * B_ + b) * PLANE * 16;
        stage(xtc, 1, 3);                       // taps only touch rows 1..3
        __syncthreads();                        // band ready
        #pragma unroll
        for (int ks = 0; ks < 9; ++ks) {
            bf16x8 a = *(const bf16x8*)&wobf[m * KTOT + cc * 144 + ks * 16 + kh * 8];
            bf16x8 s = *(const bf16x8*)&band[kh * PSTRIDE +
                        ((1 + ks / 3) * BCOLS + pxg + ks % 3 + 1) * 8];
            acc0 = __builtin_amdgcn_mfma_f32_32x32x16_bf16(a, s, acc0, 0, 0, 0);
        }
        __syncthreads();                        // reads done before restage
    }
    // offsets -> lo[mo][px] (D col = pixel = lane m -> own px tile)
    #pragma unroll
    for (int r = 0; r < 16; ++r) {
        int mo = (r & 3) + ((r >> 2) << 3) + (kh << 2);
        if (mo < MOFF) lo[mo * 128 + pxg] = acc0[r] + b_off[mo];
    }
    __syncthreads();                            // lo ready

    // ================= Phase B: deformable conv (per-wave M=64, N=32) ======
    f32x16 acc[2] = {};
    for (int cc = 0; cc < 4; ++cc) {
        const unsigned short* xtc = xt + (size_t)(cc * B_ + b) * PLANE * 16;
        stage(xtc, 0, 5);                       // full 5-row band
        __syncthreads();                        // band ready
        #pragma unroll
        for (int ks = 0; ks < 9; ++ks) {
            // sample coords from lo (stride-4B reads, 2 lanes/bank = free)
            float py  = (float)(ho - 1 + ks / 3) + lo[(2 * ks) * 128 + pxg];
            float pxc = (float)(pxg - 1 + ks % 3) + lo[(2 * ks + 1) * 128 + pxg];
            float fy = floorf(py), fx = floorf(pxc);
            float wy = py - fy,    wx = pxc - fx;
            int y0 = (int)fy, x0 = (int)fx;
            int rb = y0 - ho + 2, cb = x0 + 2;
            bool oob = ((unsigned)rb > 3u) || ((unsigned)cb > 130u);
            int rbc = min(max(rb, 0), 3), cbc = min(max(cb, 0), 130);
            const unsigned short* bp = &band[kh * PSTRIDE + (rbc * BCOLS + cbc) * 8];
            bf16x8 q00 = *(const bf16x8*)bp;
            bf16x8 q01 = *(const bf16x8*)(bp + 8);
            bf16x8 q10 = *(const bf16x8*)(bp + BCOLS * 8);
            bf16x8 q11 = *(const bf16x8*)(bp + BCOLS * 8 + 8);
            float omwy = 1.f - wy, omwx = 1.f - wx;
            float w00 = omwy * omwx, w01 = omwy * wx, w10 = wy * omwx, w11 = wy * wx;
            bf16x8 v;
            #pragma unroll
            for (int j = 0; j < 8; ++j) {
                float s = w00 * bf2f(q00[j]) + w01 * bf2f(q01[j])
                        + w10 * bf2f(q10[j]) + w11 * bf2f(q11[j]);
                v[j] = (short)f2bf(s);
            }
            // rare slow path: offsets outside the band -> exact global gather
            if (__builtin_expect(__any(oob), 0)) {
                if (oob) {
                    float s8[8];
                    #pragma unroll
                    for (int j = 0; j < 8; ++j) s8[j] = 0.f;
                    #pragma unroll
                    for (int c2 = 0; c2 < 4; ++c2) {
                        int yy = y0 + (c2 >> 1);
                        int xx = x0 + (c2 & 1);
                        bool valid = ((unsigned)yy < (unsigned)H_) && ((unsigned)xx < (unsigned)W_);
                        int yc = min(max(yy, 0), H_ - 1);
                        int xc = min(max(xx, 0), W_ - 1);
                        float wgt = ((c2 >> 1) ? wy : omwy) * ((c2 & 1) ? wx : omwx);
                        wgt = valid ? wgt : 0.f;
                        const unsigned short* rp = xtc + (yc * W_ + xc) * 16 + kh * 8;
                        bf16x8 u = *(const bf16x8*)rp;
                        #pragma unroll
                        for (int j = 0; j < 8; ++j) s8[j] += wgt * bf2f(u[j]);
                    }
                    #pragma unroll
                    for (int j = 0; j < 8; ++j) v[j] = (short)f2bf(s8[j]);
                }
            }
            // MFMA: M=64 via two A-rows; A-fragments lazy (L2-hot wbf)
            bf16x8 a0 = *(const bf16x8*)&wbf[m * KTOT + cc * 144 + ks * 16 + kh * 8];
            bf16x8 a1 = *(const bf16x8*)&wbf[(32 + m) * KTOT + cc * 144 + ks * 16 + kh * 8];
            acc[0] = __builtin_amdgcn_mfma_f32_32x32x16_bf16(a0, v, acc[0], 0, 0, 0);
            acc[1] = __builtin_amdgcn_mfma_f32_32x32x16_bf16(a1, v, acc[1], 0, 0, 0);
        }
        __syncthreads();                        // reads done before restage
    }

    // epilogue: D col = pixel (pxg), row = out channel (+32 for acc[1])
    {
        float* op = out + (size_t)b * O_ * PLANE + ho * WO_ + pxg;
        #pragma unroll
        for (int nt = 0; nt < 2; ++nt) {
            #pragma unroll
            for (int r = 0; r < 16; ++r) {
                int mo = (nt << 5) + (r & 3) + ((r >> 2) << 3) + (kh << 2);
                __builtin_nontemporal_store(acc[nt][r] + bias[mo], op + (size_t)mo * PLANE);
            }
        }
    }
}

// ---------------------------------------------------------------------------
extern "C" void kernel_launch(void* const* d_in, const int* in_sizes, int n_in,
                              void* d_out, int out_size, void* d_ws, size_t ws_size,
                              hipStream_t stream) {
    const float* x     = (const float*)d_in[0];
    const float* w_off = (const float*)d_in[1];
    const float* b_off = (const float*)d_in[2];
    const float* w     = (const float*)d_in[3];
    const float* bias  = (const float*)d_in[4];
    float* out = (float*)d_out;

    unsigned short* wbf  = (unsigned short*)d_ws;                   // 72 KB (tap-major)
    unsigned short* wobf = wbf + O_ * KTOT;                         // 36 KB (tap-major)
    unsigned short* xt   = wobf + 32 * KTOT;                        // 16.78 MB chunk-major

    const int wblocks = (96 * KTOT + 255) / 256;                    // 216
    prep_kernel <<<B_ * H_ + wblocks, 256, 0, stream>>>(x, w, w_off, xt, wbf);
    fused_kernel<<<B_ * HO_, 256, 0, stream>>>(xt, wobf, b_off, wbf, bias, out);
}